// Round 4
// baseline (366.072 us; speedup 1.0000x reference)
//
#include <hip/hip_runtime.h>
#include <hip/hip_bf16.h>

#define SEQ    2048
#define BATCH  2
#define MTOK   4096
#define EMBED  1024
#define HEADS  16
#define HDIM   64
#define QKV3   3072
#define FFN    4096

typedef __attribute__((ext_vector_type(8))) short bf16x8;
typedef __attribute__((ext_vector_type(4))) float f32x4;
typedef __attribute__((ext_vector_type(16))) float f32x16;

static __device__ __forceinline__ unsigned short f2bf(float f) {
  union { float f; unsigned u; } x; x.f = f;
  unsigned r = x.u + 0x7FFFu + ((x.u >> 16) & 1u);
  return (unsigned short)(r >> 16);
}
static __device__ __forceinline__ float bf2f(unsigned short u) {
  union { unsigned u; float f; } x; x.u = ((unsigned)u) << 16; return x.f;
}
static __device__ __forceinline__ unsigned pk2bf(float a, float b) {
#if __has_builtin(__builtin_amdgcn_cvt_pk_bf16_f32)
  typedef __attribute__((ext_vector_type(2))) __bf16 bf16x2_t;
  union { bf16x2_t v; unsigned u; } x;
  x.v = __builtin_amdgcn_cvt_pk_bf16_f32(a, b);
  return x.u;
#else
  return ((unsigned)f2bf(a)) | (((unsigned)f2bf(b)) << 16);
#endif
}
static __device__ __forceinline__ float fexp2(float x) {
#if __has_builtin(__builtin_amdgcn_exp2f)
  return __builtin_amdgcn_exp2f(x);
#else
  return exp2f(x);
#endif
}
static __device__ __forceinline__ float frcp(float x) {
#if __has_builtin(__builtin_amdgcn_rcpf)
  return __builtin_amdgcn_rcpf(x);
#else
  return 1.0f / x;
#endif
}
// gelu(v) = v * sigmoid(1.5957691*(v + 0.044715 v^3)); sigmoid via exp2.
static __device__ __forceinline__ float fgelu(float v) {
  float t = v * v;
  float z = v * __builtin_fmaf(-0.1029456f, t, -2.3022650687f);
  return v * frcp(1.0f + fexp2(z));
}

// async global->LDS, 16B per lane; lds dest is wave-uniform base + lane*16
static __device__ __forceinline__ void gload16(const unsigned short* g, unsigned short* l) {
  __builtin_amdgcn_global_load_lds((const __attribute__((address_space(1))) void*)g,
                                   (__attribute__((address_space(3))) void*)l, 16, 0, 0);
}

// ---------------- fused weight transpose + fp32->bf16: Wt[n][k] = W[k][n] (all 4 weights)
struct TD { const float* W; unsigned short* T; int K, N, ntx, base; };
struct TD4 { TD d[4]; };

__global__ void transpose_all(TD4 td) {
  __shared__ float t[32][33];
  int bid = blockIdx.x;
  int i = 0;
  if (bid >= td.d[1].base) i = 1;
  if (bid >= td.d[2].base) i = 2;
  if (bid >= td.d[3].base) i = 3;
  const TD& D = td.d[i];
  int local = bid - D.base;
  int n0 = (local % D.ntx) * 32, k0 = (local / D.ntx) * 32;
  int tx = threadIdx.x, ty = threadIdx.y;  // block (32,8)
#pragma unroll
  for (int j = 0; j < 32; j += 8)
    t[ty + j][tx] = D.W[(size_t)(k0 + ty + j) * D.N + n0 + tx];
  __syncthreads();
#pragma unroll
  for (int j = 0; j < 32; j += 8)
    D.T[(size_t)(n0 + ty + j) * D.K + k0 + tx] = f2bf(t[tx][ty + j]);
}

// ---------------- layernorm (one token per block), fp32 in -> bf16 out
__global__ __launch_bounds__(256) void ln_kernel(const float* __restrict__ in,
                                                 const float* __restrict__ w,
                                                 const float* __restrict__ b,
                                                 unsigned short* __restrict__ out) {
  __shared__ float sh[4];
  int row = blockIdx.x, tid = threadIdx.x;
  const float4 v = ((const float4*)(in + (size_t)row * EMBED))[tid];
  float s = v.x + v.y + v.z + v.w;
#pragma unroll
  for (int off = 32; off; off >>= 1) s += __shfl_xor(s, off);
  if ((tid & 63) == 0) sh[tid >> 6] = s;
  __syncthreads();
  float mean = (sh[0] + sh[1] + sh[2] + sh[3]) * (1.0f / EMBED);
  __syncthreads();
  float dx = v.x - mean, dy = v.y - mean, dz = v.z - mean, dw = v.w - mean;
  float q = dx * dx + dy * dy + dz * dz + dw * dw;
#pragma unroll
  for (int off = 32; off; off >>= 1) q += __shfl_xor(q, off);
  if ((tid & 63) == 0) sh[tid >> 6] = q;
  __syncthreads();
  float var = (sh[0] + sh[1] + sh[2] + sh[3]) * (1.0f / EMBED);
  float rs = rsqrtf(var + 1e-5f);
  const float4 wv = ((const float4*)w)[tid];
  const float4 bv = ((const float4*)b)[tid];
  ushort4 o;
  o.x = f2bf(dx * rs * wv.x + bv.x);
  o.y = f2bf(dy * rs * wv.y + bv.y);
  o.z = f2bf(dz * rs * wv.z + bv.z);
  o.w = f2bf(dw * rs * wv.w + bv.w);
  ((ushort4*)(out + (size_t)row * EMBED))[tid] = o;
}

// ---------------- 128x128 NT bf16 GEMM, BK=64, XOR-swizzled LDS (128B rows),
// plain n-fastest block order (XCD x statically owns n === x mod 8 -> B slice L2-resident).
template <int ACT, int OUTBF, int VSPLIT>
__global__ __launch_bounds__(256) void gemmBig(const unsigned short* __restrict__ A,
                                               const unsigned short* __restrict__ Wt,
                                               const float* __restrict__ bias,
                                               unsigned short* __restrict__ outB,
                                               float* __restrict__ outF,
                                               unsigned short* __restrict__ vT,
                                               int M, int N, int K, int nblk) {
  __shared__ __align__(16) unsigned short As[128 * 64];  // 16 KB
  __shared__ __align__(16) unsigned short Bs[128 * 64];  // 16 KB
  const int tid = threadIdx.x;
  const int wave = tid >> 6, lane = tid & 63;
  const int quad = lane >> 4, ml = lane & 15;
  const int wr = wave >> 1, wc = wave & 1;
  const int m0 = (blockIdx.x / nblk) * 128;
  const int n0 = (blockIdx.x % nblk) * 128;
  const int srow = lane >> 3;
  const int schunk = (lane & 7) ^ (srow & 7);
  const unsigned short* Ag = A + (size_t)(m0 + wave * 32 + srow) * K + schunk * 8;
  const unsigned short* Bg = Wt + (size_t)(n0 + wave * 32 + srow) * K + schunk * 8;
  unsigned short* AsW = &As[wave * 2048];
  unsigned short* BsW = &Bs[wave * 2048];
  f32x4 acc[4][4];
#pragma unroll
  for (int i = 0; i < 4; i++)
#pragma unroll
    for (int j = 0; j < 4; j++) acc[i][j] = (f32x4){0.f, 0.f, 0.f, 0.f};
  for (int k0 = 0; k0 < K; k0 += 64) {
    __syncthreads();
#pragma unroll
    for (int t = 0; t < 4; t++) {
      gload16(Ag + (size_t)(8 * t) * K, AsW + 512 * t);
      gload16(Bg + (size_t)(8 * t) * K, BsW + 512 * t);
    }
    Ag += 64; Bg += 64;
    __syncthreads();
#pragma unroll
    for (int kh = 0; kh < 2; kh++) {
      const int ch = ((kh * 4 + quad) ^ (ml & 7)) * 8;
      bf16x8 af[4], bfr[4];
#pragma unroll
      for (int mt = 0; mt < 4; mt++)
        af[mt] = *(const bf16x8*)&As[(wr * 64 + mt * 16 + ml) * 64 + ch];
#pragma unroll
      for (int nt = 0; nt < 4; nt++)
        bfr[nt] = *(const bf16x8*)&Bs[(wc * 64 + nt * 16 + ml) * 64 + ch];
#pragma unroll
      for (int mt = 0; mt < 4; mt++)
#pragma unroll
        for (int nt = 0; nt < 4; nt++)
          acc[mt][nt] = __builtin_amdgcn_mfma_f32_16x16x32_bf16(af[mt], bfr[nt], acc[mt][nt], 0, 0, 0);
    }
  }
#pragma unroll
  for (int mt = 0; mt < 4; mt++)
#pragma unroll
    for (int nt = 0; nt < 4; nt++) {
      const int col0 = n0 + wc * 64 + nt * 16;
      const int row0 = m0 + wr * 64 + mt * 16;
      if (VSPLIT && col0 >= 2 * EMBED) {
        const int b = row0 >> 11, tok0 = row0 & (SEQ - 1);
        const int h = (col0 - 2 * EMBED) >> 6;
        const int dl = ((col0 - 2 * EMBED) & 63) + ml;
        float bia = bias[col0 + ml];
        ushort4 o;
        o.x = f2bf(acc[mt][nt][0] + bia);
        o.y = f2bf(acc[mt][nt][1] + bia);
        o.z = f2bf(acc[mt][nt][2] + bia);
        o.w = f2bf(acc[mt][nt][3] + bia);
        *(ushort4*)(vT + (size_t)((b * 16 + h) * 64 + dl) * SEQ + tok0 + quad * 4) = o;
      } else {
#pragma unroll
        for (int r = 0; r < 4; r++) {
          int row = row0 + quad * 4 + r;
          int col = col0 + ml;
          float v = acc[mt][nt][r] + bias[col];
          if (ACT) v = fgelu(v);
          if (OUTBF)
            outB[(size_t)row * N + col] = f2bf(v);
          else
            outF[(size_t)row * N + col] = v;
        }
      }
    }
}

// ---------------- 128x64 NT GEMM, BK=64, XOR-swizzled LDS, XCD m-stripe grid.
// v3: 2-phase double-buffered prefetch (T3-min): grid shape-pinned at 2 blocks/CU,
// prefetch-before-compute + one barrier/iter reclaims exposed stage latency.
template <int RES, int OUTBF>
__global__ __launch_bounds__(256) void gemm64k(const unsigned short* __restrict__ A,
                                               const unsigned short* __restrict__ Wt,
                                               const float* __restrict__ bias,
                                               const float* __restrict__ res,
                                               unsigned short* __restrict__ outB,
                                               float* __restrict__ outF,
                                               int M, int N, int K, int nblk) {
  __shared__ __align__(16) unsigned short As[2][128 * 64];  // 32 KB
  __shared__ __align__(16) unsigned short Bs[2][64 * 64];   // 16 KB
  const int tid = threadIdx.x;
  const int wave = tid >> 6, lane = tid & 63;
  const int quad = lane >> 4, ml = lane & 15;
  const int wr = wave >> 1, wc = wave & 1;
  const int xcd = blockIdx.x & 7, idx = blockIdx.x >> 3;
  const int mPerXcd = (gridDim.x >> 3) / nblk;
  const int m0 = (xcd * mPerXcd + idx / nblk) * 128;
  const int n0 = (idx % nblk) * 64;
  const int srow = lane >> 3;
  const int schunk = (lane & 7) ^ (srow & 7);
  const unsigned short* Ag = A + (size_t)(m0 + wave * 32 + srow) * K + schunk * 8;
  const unsigned short* Bg = Wt + (size_t)(n0 + wave * 16 + srow) * K + schunk * 8;
  f32x4 acc[4][2];
#pragma unroll
  for (int i = 0; i < 4; i++) { acc[i][0] = (f32x4){0.f,0.f,0.f,0.f}; acc[i][1] = acc[i][0]; }
  {
    unsigned short* AsW = &As[0][wave * 2048];
    unsigned short* BsW = &Bs[0][wave * 1024];
    gload16(Ag, AsW);
    gload16(Ag + (size_t)8 * K,  AsW + 512);
    gload16(Ag + (size_t)16 * K, AsW + 1024);
    gload16(Ag + (size_t)24 * K, AsW + 1536);
    gload16(Bg, BsW);
    gload16(Bg + (size_t)8 * K,  BsW + 512);
    Ag += 64; Bg += 64;
  }
  __syncthreads();
  const int nk = K >> 6;
  for (int kk = 0; kk < nk; ++kk) {
    const int cur = kk & 1;
    if (kk + 1 < nk) {
      unsigned short* AsW = &As[cur ^ 1][wave * 2048];
      unsigned short* BsW = &Bs[cur ^ 1][wave * 1024];
      gload16(Ag, AsW);
      gload16(Ag + (size_t)8 * K,  AsW + 512);
      gload16(Ag + (size_t)16 * K, AsW + 1024);
      gload16(Ag + (size_t)24 * K, AsW + 1536);
      gload16(Bg, BsW);
      gload16(Bg + (size_t)8 * K,  BsW + 512);
      Ag += 64; Bg += 64;
    }
#pragma unroll
    for (int kh = 0; kh < 2; kh++) {
      const int ch = ((kh * 4 + quad) ^ (ml & 7)) * 8;
      bf16x8 af[4], bfr[2];
#pragma unroll
      for (int mt = 0; mt < 4; mt++)
        af[mt] = *(const bf16x8*)&As[cur][(wr * 64 + mt * 16 + ml) * 64 + ch];
#pragma unroll
      for (int nt = 0; nt < 2; nt++)
        bfr[nt] = *(const bf16x8*)&Bs[cur][(wc * 32 + nt * 16 + ml) * 64 + ch];
#pragma unroll
      for (int mt = 0; mt < 4; mt++)
#pragma unroll
        for (int nt = 0; nt < 2; nt++)
          acc[mt][nt] = __builtin_amdgcn_mfma_f32_16x16x32_bf16(af[mt], bfr[nt], acc[mt][nt], 0, 0, 0);
    }
    __syncthreads();
  }
#pragma unroll
  for (int mt = 0; mt < 4; mt++)
#pragma unroll
    for (int nt = 0; nt < 2; nt++)
#pragma unroll
      for (int r = 0; r < 4; r++) {
        int row = m0 + wr * 64 + mt * 16 + quad * 4 + r;
        int col = n0 + wc * 32 + nt * 16 + ml;
        float v = acc[mt][nt][r] + bias[col];
        if (RES) v += res[(size_t)row * N + col];
        if (OUTBF)
          outB[(size_t)row * N + col] = f2bf(v);
        else
          outF[(size_t)row * N + col] = v;
      }
}

// ---------------- flash attention v3: 32x32x16 MFMA + in-register softmax (T12).
// grid (x = bh FAST, y = q-tile of 128): q-tiles of one bh share bid%8 -> same XCD.
// Wave owns 32 q-rows (q = q0w + lane&31). Swapped QK^T: St^T[key][q] per 32-key tile,
// lane holds 16 keys for its q-column. exp2 -> cvt_pk -> lane^32 butterfly assembles
// PV A-fragments IN REGISTER (no P LDS round-trip, no P bank conflicts).
// Fragment layouts (gfx950, verified via m214 structure):
//   A[row=lane&31][k=(lane>>5)*8+j]   B[col=lane&31][k=(lane>>5)*8+j]
//   D[col=lane&31][row=(r&3)+8*(r>>2)+4*(lane>>5)]
// K/V staging identical to v2 (double-buffered, row-XOR swizzle). LDS = 32 KB.
__global__ __launch_bounds__(256, 2) void attn_kernel(const unsigned short* __restrict__ qkv,
                                                      const unsigned short* __restrict__ vT,
                                                      unsigned short* __restrict__ attn) {
  __shared__ __align__(16) unsigned short Ks[2][64 * 64];  // 16 KB
  __shared__ __align__(16) unsigned short Vs[2][64 * 64];  // 16 KB
  const int tid = threadIdx.x, wave = tid >> 6, lane = tid & 63;
  const int l31 = lane & 31, hi = lane >> 5;
  const int bh = blockIdx.x, b = bh >> 4, h = bh & 15;   // bh = fast grid axis
  const int q0w = blockIdx.y * 128 + wave * 32;
  const float qscale = 0.18033688011112042f;  // 0.125 * log2(e)
  const int sw = l31 & 7;

  // Q fragments (B-operand of swapped QK^T): bq[s] = Q[q0w+l31][s*16 + hi*8 + j] * qscale
  const unsigned short* qrow = qkv + (size_t)(b * SEQ + q0w + l31) * QKV3 + h * HDIM;
  bf16x8 bq[4];
#pragma unroll
  for (int s = 0; s < 4; s++) {
    bq[s] = *(const bf16x8*)(qrow + s * 16 + hi * 8);
#pragma unroll
    for (int j = 0; j < 8; j++)
      bq[s][j] = (short)f2bf(bf2f((unsigned short)bq[s][j]) * qscale);
  }
  bf16x8 ones;
#pragma unroll
  for (int j = 0; j < 8; j++) ones[j] = (short)0x3F80;  // bf16 1.0

  f32x16 zz;
#pragma unroll
  for (int i = 0; i < 16; i++) zz[i] = 0.f;
  f32x16 O0 = zz, O1 = zz, lsum = zz;

  // staging (identical scheme to v2): wave stages 16 K-rows (keys) and 16 V-rows (d)
  const int skey = lane >> 3;
  const int schunk8 = ((lane & 7) ^ (skey & 7)) * 8;
  const unsigned short* kbase =
      qkv + (size_t)(b * SEQ + wave * 16 + skey) * QKV3 + EMBED + h * HDIM + schunk8;
  const unsigned short* vbase =
      vT + (size_t)(bh * 64 + wave * 16 + skey) * SEQ + schunk8;

  // prologue: stage tile 0 into buffer 0
  gload16(kbase, &Ks[0][wave * 1024]);
  gload16(kbase + (size_t)8 * QKV3, &Ks[0][wave * 1024] + 512);
  gload16(vbase, &Vs[0][wave * 1024]);
  gload16(vbase + (size_t)8 * SEQ, &Vs[0][wave * 1024] + 512);
  __syncthreads();  // vmcnt drain: tile 0 resident

  for (int kti = 0; kti < SEQ / 64; ++kti) {
    const int cur = kti & 1;
    // prefetch next tile (latency hides under this tile's compute)
    if (kti + 1 < SEQ / 64) {
      const int kt = (kti + 1) * 64;
      unsigned short* kd = &Ks[cur ^ 1][wave * 1024];
      unsigned short* vd = &Vs[cur ^ 1][wave * 1024];
      gload16(kbase + (size_t)kt * QKV3, kd);
      gload16(kbase + (size_t)(kt + 8) * QKV3, kd + 512);
      gload16(vbase + kt, vd);
      gload16(vbase + kt + (size_t)8 * SEQ, vd + 512);
    }
    const unsigned short* Kc = &Ks[cur][0];
    const unsigned short* Vc = &Vs[cur][0];

    // QK^T: St[kt2]^T[key][q], kt2 = 32-key subtile. A = K rows, B = Q.
    f32x16 St0 = zz, St1 = zz;
#pragma unroll
    for (int s = 0; s < 4; s++) {
      bf16x8 ak0 = *(const bf16x8*)&Kc[l31 * 64 + (((2 * s + hi) ^ sw)) * 8];
      bf16x8 ak1 = *(const bf16x8*)&Kc[(32 + l31) * 64 + (((2 * s + hi) ^ sw)) * 8];
      St0 = __builtin_amdgcn_mfma_f32_32x32x16_bf16(ak0, bq[s], St0, 0, 0, 0);
      St1 = __builtin_amdgcn_mfma_f32_32x32x16_bf16(ak1, bq[s], St1, 0, 0, 0);
    }

    // exp2 + pack: lane holds P[q=l31][key = kt2*32 + (r&3)+8*(r>>2)+4*hi].
    // W0[kt2][g] = packed keys (8g+4hi+0, +1); W1 = (+2, +3).
    unsigned W0[2][4], W1[2][4];
#pragma unroll
    for (int g = 0; g < 4; g++) {
      W0[0][g] = pk2bf(fexp2(St0[4 * g]), fexp2(St0[4 * g + 1]));
      W1[0][g] = pk2bf(fexp2(St0[4 * g + 2]), fexp2(St0[4 * g + 3]));
      W0[1][g] = pk2bf(fexp2(St1[4 * g]), fexp2(St1[4 * g + 1]));
      W1[1][g] = pk2bf(fexp2(St1[4 * g + 2]), fexp2(St1[4 * g + 3]));
    }

    // T12 assembly: pa[ks] = A-frag P[q=l31][keys ks*16 + hi*8 + j] via lane^32 butterfly.
    // ks: kt2 = ks>>1, g0 = 2*(ks&1), g1 = g0+1.
    //  word0 = hi ? partner.w0(g1) : own.w0(g0)   word2 = hi ? own.w0(g1) : partner.w0(g0)
    bf16x8 pa[4];
#pragma unroll
    for (int ks = 0; ks < 4; ks++) {
      const int kt2 = ks >> 1, g0 = 2 * (ks & 1), g1 = g0 + 1;
      unsigned send0 = hi ? W0[kt2][g0] : W0[kt2][g1];
      unsigned send1 = hi ? W1[kt2][g0] : W1[kt2][g1];
      unsigned recv0 = __shfl_xor((int)send0, 32);
      unsigned recv1 = __shfl_xor((int)send1, 32);
      union { unsigned u[4]; bf16x8 v; } pw;
      pw.u[0] = hi ? recv0 : W0[kt2][g0];
      pw.u[1] = hi ? recv1 : W1[kt2][g0];
      pw.u[2] = hi ? W0[kt2][g1] : recv0;
      pw.u[3] = hi ? W1[kt2][g1] : recv1;
      pa[ks] = pw.v;
    }

    // lsum (MFMA-ones: D rows = q, same row mapping as O) + PV
    __builtin_amdgcn_s_setprio(1);
#pragma unroll
    for (int ks = 0; ks < 4; ks++)
      lsum = __builtin_amdgcn_mfma_f32_32x32x16_bf16(pa[ks], ones, lsum, 0, 0, 0);
#pragma unroll
    for (int ks = 0; ks < 4; ks++) {
      bf16x8 bv0 = *(const bf16x8*)&Vc[l31 * 64 + (((2 * ks + hi) ^ sw)) * 8];
      bf16x8 bv1 = *(const bf16x8*)&Vc[(32 + l31) * 64 + (((2 * ks + hi) ^ sw)) * 8];
      O0 = __builtin_amdgcn_mfma_f32_32x32x16_bf16(pa[ks], bv0, O0, 0, 0, 0);
      O1 = __builtin_amdgcn_mfma_f32_32x32x16_bf16(pa[ks], bv1, O1, 0, 0, 0);
    }
    __builtin_amdgcn_s_setprio(0);
    __syncthreads();
  }

  // epilogue: O/lsum rows share the D mapping q = (r&3)+8*(r>>2)+4*hi
#pragma unroll
  for (int r = 0; r < 16; r++) {
    const int qr = (r & 3) + 8 * (r >> 2) + 4 * hi;
    float inv = 1.0f / lsum[r];
    size_t g = (size_t)(b * SEQ + q0w + qr) * EMBED + h * HDIM + l31;
    attn[g]      = f2bf(O0[r] * inv);
    attn[g + 32] = f2bf(O1[r] * inv);
  }
}

extern "C" void kernel_launch(void* const* d_in, const int* in_sizes, int n_in,
                              void* d_out, int out_size, void* d_ws, size_t ws_size,
                              hipStream_t stream) {
  const float* x      = (const float*)d_in[0];
  const float* ln1_w  = (const float*)d_in[1];
  const float* ln1_b  = (const float*)d_in[2];
  const float* ln2_w  = (const float*)d_in[3];
  const float* ln2_b  = (const float*)d_in[4];
  const float* qkv_w  = (const float*)d_in[5];
  const float* qkv_b  = (const float*)d_in[6];
  const float* proj_w = (const float*)d_in[7];
  const float* proj_b = (const float*)d_in[8];
  const float* fc1_w  = (const float*)d_in[9];
  const float* fc1_b  = (const float*)d_in[10];
  const float* fc2_w  = (const float*)d_in[11];
  const float* fc2_b  = (const float*)d_in[12];
  float* out = (float*)d_out;
  char* wsb = (char*)d_ws;
  unsigned short* lnbuf  = (unsigned short*)(wsb + 0);
  unsigned short* qkvb   = (unsigned short*)(wsb + 8388608);
  unsigned short* attnb  = (unsigned short*)(wsb + 33554432);
  unsigned short* vTb    = (unsigned short*)(wsb + 41943040);
  unsigned short* actb   = (unsigned short*)(wsb + 33554432);
  float*          h1     = (float*)(wsb + 67108864);
  unsigned short* qkvWt  = (unsigned short*)(wsb + 83886080);
  unsigned short* projWt = (unsigned short*)(wsb + 90177536);
  unsigned short* fc1Wt  = (unsigned short*)(wsb + 92274688);
  unsigned short* fc2Wt  = (unsigned short*)(wsb + 100663296);

  TD4 td;
  td.d[0] = {qkv_w,  qkvWt,  1024, 3072,  96, 0};
  td.d[1] = {proj_w, projWt, 1024, 1024,  32, 3072};
  td.d[2] = {fc1_w,  fc1Wt,  1024, 4096, 128, 4096};
  td.d[3] = {fc2_w,  fc2Wt,  4096, 1024,  32, 8192};
  transpose_all<<<12288, dim3(32, 8), 0, stream>>>(td);

  ln_kernel<<<MTOK, 256, 0, stream>>>(x, ln1_w, ln1_b, lnbuf);
  gemmBig<0, 1, 1><<<768, 256, 0, stream>>>(
      lnbuf, qkvWt, qkv_b, qkvb, nullptr, vTb, MTOK, QKV3, EMBED, 24);
  attn_kernel<<<dim3(32, 16), 256, 0, stream>>>(qkvb, vTb, attnb);
  gemm64k<1, 0><<<512, 256, 0, stream>>>(
      attnb, projWt, proj_b, x, nullptr, h1, MTOK, EMBED, EMBED, 16);
  ln_kernel<<<MTOK, 256, 0, stream>>>(h1, ln2_w, ln2_b, lnbuf);
  gemmBig<1, 1, 0><<<1024, 256, 0, stream>>>(
      lnbuf, fc1Wt, fc1_b, actb, nullptr, nullptr, MTOK, FFN, EMBED, 32);
  gemm64k<1, 0><<<512, 256, 0, stream>>>(
      actb, fc2Wt, fc2_b, h1, nullptr, out, MTOK, EMBED, FFN, 16);
}

// Round 5
// 343.542 us; speedup vs baseline: 1.0656x; 1.0656x over previous
//
#include <hip/hip_runtime.h>
#include <hip/hip_bf16.h>

#define SEQ    2048
#define BATCH  2
#define MTOK   4096
#define EMBED  1024
#define HEADS  16
#define HDIM   64
#define QKV3   3072
#define FFN    4096

typedef __attribute__((ext_vector_type(8))) short bf16x8;
typedef __attribute__((ext_vector_type(4))) float f32x4;
typedef __attribute__((ext_vector_type(16))) float f32x16;

static __device__ __forceinline__ unsigned short f2bf(float f) {
  union { float f; unsigned u; } x; x.f = f;
  unsigned r = x.u + 0x7FFFu + ((x.u >> 16) & 1u);
  return (unsigned short)(r >> 16);
}
static __device__ __forceinline__ float bf2f(unsigned short u) {
  union { unsigned u; float f; } x; x.u = ((unsigned)u) << 16; return x.f;
}
static __device__ __forceinline__ unsigned pk2bf(float a, float b) {
#if __has_builtin(__builtin_amdgcn_cvt_pk_bf16_f32)
  typedef __attribute__((ext_vector_type(2))) __bf16 bf16x2_t;
  union { bf16x2_t v; unsigned u; } x;
  x.v = __builtin_amdgcn_cvt_pk_bf16_f32(a, b);
  return x.u;
#else
  return ((unsigned)f2bf(a)) | (((unsigned)f2bf(b)) << 16);
#endif
}
static __device__ __forceinline__ float fexp2(float x) {
#if __has_builtin(__builtin_amdgcn_exp2f)
  return __builtin_amdgcn_exp2f(x);
#else
  return exp2f(x);
#endif
}
static __device__ __forceinline__ float frcp(float x) {
#if __has_builtin(__builtin_amdgcn_rcpf)
  return __builtin_amdgcn_rcpf(x);
#else
  return 1.0f / x;
#endif
}
// gelu(v) = v * sigmoid(1.5957691*(v + 0.044715 v^3)); sigmoid via exp2.
static __device__ __forceinline__ float fgelu(float v) {
  float t = v * v;
  float z = v * __builtin_fmaf(-0.1029456f, t, -2.3022650687f);
  return v * frcp(1.0f + fexp2(z));
}

// half-swap across the lane<32 / lane>=32 split:
//   lo_out = concat(a[0:32], b[0:32])   hi_out = concat(a[32:64], b[32:64])
static __device__ __forceinline__ void halfswap(unsigned a, unsigned b, int hi,
                                                unsigned& lo_out, unsigned& hi_out) {
#if __has_builtin(__builtin_amdgcn_permlane32_swap)
  typedef __attribute__((ext_vector_type(2))) unsigned uint2v;
  uint2v r = __builtin_amdgcn_permlane32_swap(a, b, false, false);
  lo_out = r[0];
  hi_out = r[1];
#else
  unsigned as = (unsigned)__shfl_xor((int)a, 32);
  unsigned bs = (unsigned)__shfl_xor((int)b, 32);
  lo_out = hi ? bs : a;
  hi_out = hi ? b : as;
#endif
}

// async global->LDS, 16B per lane; lds dest is wave-uniform base + lane*16
static __device__ __forceinline__ void gload16(const unsigned short* g, unsigned short* l) {
  __builtin_amdgcn_global_load_lds((const __attribute__((address_space(1))) void*)g,
                                   (__attribute__((address_space(3))) void*)l, 16, 0, 0);
}

// ---------------- fused weight transpose + fp32->bf16: Wt[n][k] = W[k][n] (all 4 weights)
struct TD { const float* W; unsigned short* T; int K, N, ntx, base; };
struct TD4 { TD d[4]; };

__global__ void transpose_all(TD4 td) {
  __shared__ float t[32][33];
  int bid = blockIdx.x;
  int i = 0;
  if (bid >= td.d[1].base) i = 1;
  if (bid >= td.d[2].base) i = 2;
  if (bid >= td.d[3].base) i = 3;
  const TD& D = td.d[i];
  int local = bid - D.base;
  int n0 = (local % D.ntx) * 32, k0 = (local / D.ntx) * 32;
  int tx = threadIdx.x, ty = threadIdx.y;  // block (32,8)
#pragma unroll
  for (int j = 0; j < 32; j += 8)
    t[ty + j][tx] = D.W[(size_t)(k0 + ty + j) * D.N + n0 + tx];
  __syncthreads();
#pragma unroll
  for (int j = 0; j < 32; j += 8)
    D.T[(size_t)(n0 + ty + j) * D.K + k0 + tx] = f2bf(t[tx][ty + j]);
}

// ---------------- layernorm (one token per block), fp32 in -> bf16 out
__global__ __launch_bounds__(256) void ln_kernel(const float* __restrict__ in,
                                                 const float* __restrict__ w,
                                                 const float* __restrict__ b,
                                                 unsigned short* __restrict__ out) {
  __shared__ float sh[4];
  int row = blockIdx.x, tid = threadIdx.x;
  const float4 v = ((const float4*)(in + (size_t)row * EMBED))[tid];
  float s = v.x + v.y + v.z + v.w;
#pragma unroll
  for (int off = 32; off; off >>= 1) s += __shfl_xor(s, off);
  if ((tid & 63) == 0) sh[tid >> 6] = s;
  __syncthreads();
  float mean = (sh[0] + sh[1] + sh[2] + sh[3]) * (1.0f / EMBED);
  __syncthreads();
  float dx = v.x - mean, dy = v.y - mean, dz = v.z - mean, dw = v.w - mean;
  float q = dx * dx + dy * dy + dz * dz + dw * dw;
#pragma unroll
  for (int off = 32; off; off >>= 1) q += __shfl_xor(q, off);
  if ((tid & 63) == 0) sh[tid >> 6] = q;
  __syncthreads();
  float var = (sh[0] + sh[1] + sh[2] + sh[3]) * (1.0f / EMBED);
  float rs = rsqrtf(var + 1e-5f);
  const float4 wv = ((const float4*)w)[tid];
  const float4 bv = ((const float4*)b)[tid];
  ushort4 o;
  o.x = f2bf(dx * rs * wv.x + bv.x);
  o.y = f2bf(dy * rs * wv.y + bv.y);
  o.z = f2bf(dz * rs * wv.z + bv.z);
  o.w = f2bf(dw * rs * wv.w + bv.w);
  ((ushort4*)(out + (size_t)row * EMBED))[tid] = o;
}

// ---------------- 128x128 NT bf16 GEMM, BK=64, XOR-swizzled LDS (128B rows),
// plain n-fastest block order (XCD x statically owns n === x mod 8 -> B slice L2-resident).
template <int ACT, int OUTBF, int VSPLIT>
__global__ __launch_bounds__(256) void gemmBig(const unsigned short* __restrict__ A,
                                               const unsigned short* __restrict__ Wt,
                                               const float* __restrict__ bias,
                                               unsigned short* __restrict__ outB,
                                               float* __restrict__ outF,
                                               unsigned short* __restrict__ vT,
                                               int M, int N, int K, int nblk) {
  __shared__ __align__(16) unsigned short As[128 * 64];  // 16 KB
  __shared__ __align__(16) unsigned short Bs[128 * 64];  // 16 KB
  const int tid = threadIdx.x;
  const int wave = tid >> 6, lane = tid & 63;
  const int quad = lane >> 4, ml = lane & 15;
  const int wr = wave >> 1, wc = wave & 1;
  const int m0 = (blockIdx.x / nblk) * 128;
  const int n0 = (blockIdx.x % nblk) * 128;
  const int srow = lane >> 3;
  const int schunk = (lane & 7) ^ (srow & 7);
  const unsigned short* Ag = A + (size_t)(m0 + wave * 32 + srow) * K + schunk * 8;
  const unsigned short* Bg = Wt + (size_t)(n0 + wave * 32 + srow) * K + schunk * 8;
  unsigned short* AsW = &As[wave * 2048];
  unsigned short* BsW = &Bs[wave * 2048];
  f32x4 acc[4][4];
#pragma unroll
  for (int i = 0; i < 4; i++)
#pragma unroll
    for (int j = 0; j < 4; j++) acc[i][j] = (f32x4){0.f, 0.f, 0.f, 0.f};
  for (int k0 = 0; k0 < K; k0 += 64) {
    __syncthreads();
#pragma unroll
    for (int t = 0; t < 4; t++) {
      gload16(Ag + (size_t)(8 * t) * K, AsW + 512 * t);
      gload16(Bg + (size_t)(8 * t) * K, BsW + 512 * t);
    }
    Ag += 64; Bg += 64;
    __syncthreads();
#pragma unroll
    for (int kh = 0; kh < 2; kh++) {
      const int ch = ((kh * 4 + quad) ^ (ml & 7)) * 8;
      bf16x8 af[4], bfr[4];
#pragma unroll
      for (int mt = 0; mt < 4; mt++)
        af[mt] = *(const bf16x8*)&As[(wr * 64 + mt * 16 + ml) * 64 + ch];
#pragma unroll
      for (int nt = 0; nt < 4; nt++)
        bfr[nt] = *(const bf16x8*)&Bs[(wc * 64 + nt * 16 + ml) * 64 + ch];
#pragma unroll
      for (int mt = 0; mt < 4; mt++)
#pragma unroll
        for (int nt = 0; nt < 4; nt++)
          acc[mt][nt] = __builtin_amdgcn_mfma_f32_16x16x32_bf16(af[mt], bfr[nt], acc[mt][nt], 0, 0, 0);
    }
  }
#pragma unroll
  for (int mt = 0; mt < 4; mt++)
#pragma unroll
    for (int nt = 0; nt < 4; nt++) {
      const int col0 = n0 + wc * 64 + nt * 16;
      const int row0 = m0 + wr * 64 + mt * 16;
      if (VSPLIT && col0 >= 2 * EMBED) {
        const int b = row0 >> 11, tok0 = row0 & (SEQ - 1);
        const int h = (col0 - 2 * EMBED) >> 6;
        const int dl = ((col0 - 2 * EMBED) & 63) + ml;
        float bia = bias[col0 + ml];
        ushort4 o;
        o.x = f2bf(acc[mt][nt][0] + bia);
        o.y = f2bf(acc[mt][nt][1] + bia);
        o.z = f2bf(acc[mt][nt][2] + bia);
        o.w = f2bf(acc[mt][nt][3] + bia);
        *(ushort4*)(vT + (size_t)((b * 16 + h) * 64 + dl) * SEQ + tok0 + quad * 4) = o;
      } else {
#pragma unroll
        for (int r = 0; r < 4; r++) {
          int row = row0 + quad * 4 + r;
          int col = col0 + ml;
          float v = acc[mt][nt][r] + bias[col];
          if (ACT) v = fgelu(v);
          if (OUTBF)
            outB[(size_t)row * N + col] = f2bf(v);
          else
            outF[(size_t)row * N + col] = v;
        }
      }
    }
}

// ---------------- 128x64 NT GEMM, BK=64, XOR-swizzled LDS, XCD m-stripe grid.
// v3: 2-phase double-buffered prefetch (T3-min): grid shape-pinned at 2 blocks/CU,
// prefetch-before-compute + one barrier/iter reclaims exposed stage latency.
template <int RES, int OUTBF>
__global__ __launch_bounds__(256) void gemm64k(const unsigned short* __restrict__ A,
                                               const unsigned short* __restrict__ Wt,
                                               const float* __restrict__ bias,
                                               const float* __restrict__ res,
                                               unsigned short* __restrict__ outB,
                                               float* __restrict__ outF,
                                               int M, int N, int K, int nblk) {
  __shared__ __align__(16) unsigned short As[2][128 * 64];  // 32 KB
  __shared__ __align__(16) unsigned short Bs[2][64 * 64];   // 16 KB
  const int tid = threadIdx.x;
  const int wave = tid >> 6, lane = tid & 63;
  const int quad = lane >> 4, ml = lane & 15;
  const int wr = wave >> 1, wc = wave & 1;
  const int xcd = blockIdx.x & 7, idx = blockIdx.x >> 3;
  const int mPerXcd = (gridDim.x >> 3) / nblk;
  const int m0 = (xcd * mPerXcd + idx / nblk) * 128;
  const int n0 = (idx % nblk) * 64;
  const int srow = lane >> 3;
  const int schunk = (lane & 7) ^ (srow & 7);
  const unsigned short* Ag = A + (size_t)(m0 + wave * 32 + srow) * K + schunk * 8;
  const unsigned short* Bg = Wt + (size_t)(n0 + wave * 16 + srow) * K + schunk * 8;
  f32x4 acc[4][2];
#pragma unroll
  for (int i = 0; i < 4; i++) { acc[i][0] = (f32x4){0.f,0.f,0.f,0.f}; acc[i][1] = acc[i][0]; }
  {
    unsigned short* AsW = &As[0][wave * 2048];
    unsigned short* BsW = &Bs[0][wave * 1024];
    gload16(Ag, AsW);
    gload16(Ag + (size_t)8 * K,  AsW + 512);
    gload16(Ag + (size_t)16 * K, AsW + 1024);
    gload16(Ag + (size_t)24 * K, AsW + 1536);
    gload16(Bg, BsW);
    gload16(Bg + (size_t)8 * K,  BsW + 512);
    Ag += 64; Bg += 64;
  }
  __syncthreads();
  const int nk = K >> 6;
  for (int kk = 0; kk < nk; ++kk) {
    const int cur = kk & 1;
    if (kk + 1 < nk) {
      unsigned short* AsW = &As[cur ^ 1][wave * 2048];
      unsigned short* BsW = &Bs[cur ^ 1][wave * 1024];
      gload16(Ag, AsW);
      gload16(Ag + (size_t)8 * K,  AsW + 512);
      gload16(Ag + (size_t)16 * K, AsW + 1024);
      gload16(Ag + (size_t)24 * K, AsW + 1536);
      gload16(Bg, BsW);
      gload16(Bg + (size_t)8 * K,  BsW + 512);
      Ag += 64; Bg += 64;
    }
#pragma unroll
    for (int kh = 0; kh < 2; kh++) {
      const int ch = ((kh * 4 + quad) ^ (ml & 7)) * 8;
      bf16x8 af[4], bfr[2];
#pragma unroll
      for (int mt = 0; mt < 4; mt++)
        af[mt] = *(const bf16x8*)&As[cur][(wr * 64 + mt * 16 + ml) * 64 + ch];
#pragma unroll
      for (int nt = 0; nt < 2; nt++)
        bfr[nt] = *(const bf16x8*)&Bs[cur][(wc * 32 + nt * 16 + ml) * 64 + ch];
#pragma unroll
      for (int mt = 0; mt < 4; mt++)
#pragma unroll
        for (int nt = 0; nt < 2; nt++)
          acc[mt][nt] = __builtin_amdgcn_mfma_f32_16x16x32_bf16(af[mt], bfr[nt], acc[mt][nt], 0, 0, 0);
    }
    __syncthreads();
  }
#pragma unroll
  for (int mt = 0; mt < 4; mt++)
#pragma unroll
    for (int nt = 0; nt < 2; nt++)
#pragma unroll
      for (int r = 0; r < 4; r++) {
        int row = m0 + wr * 64 + mt * 16 + quad * 4 + r;
        int col = n0 + wc * 32 + nt * 16 + ml;
        float v = acc[mt][nt][r] + bias[col];
        if (RES) v += res[(size_t)row * N + col];
        if (OUTBF)
          outB[(size_t)row * N + col] = f2bf(v);
        else
          outF[(size_t)row * N + col] = v;
      }
}

// ---------------- flash attention v4: 32x32x16 MFMA + in-reg softmax + KEY-SPLIT waves.
// grid (x = bh FAST, y = 32 q-tiles of 64): q-tiles of one bh share bid%8 -> same XCD.
// Block = 4 waves: (qs, kh) = (wave&1, wave>>1). Wave owns 32 q rows (q0w + l31) and
// processes keys [kh*32, kh*32+32) of each 64-key tile -> per-wave work halves, grid
// doubles -> 4 waves/SIMD (v3 had 2: latency-bound at Occupancy 18%). Softmax has no
// running max (pure sum of exp2), so key-split partials merge LINEARLY once at the end
// via a 24 KB LDS exchange (reusing K/V buffers).
// pa assembly in-register via permlane32_swap (T12) with shfl fallback.
// Fragment layouts (gfx950): A[row=l31][k=hi*8+j]  B[col=l31][k=hi*8+j]
//   D[col=l31][row=(r&3)+8*(r>>2)+4*hi]
__global__ __launch_bounds__(256, 4) void attn_kernel(const unsigned short* __restrict__ qkv,
                                                      const unsigned short* __restrict__ vT,
                                                      unsigned short* __restrict__ attn) {
  __shared__ __align__(16) unsigned short Ks[2][64 * 64];  // 16 KB
  __shared__ __align__(16) unsigned short Vs[2][64 * 64];  // 16 KB
  const int tid = threadIdx.x, wave = tid >> 6, lane = tid & 63;
  const int l31 = lane & 31, hi = lane >> 5;
  const int qs = wave & 1, kh = wave >> 1;
  const int bh = blockIdx.x, b = bh >> 4, h = bh & 15;   // bh = fast grid axis
  const int q0w = blockIdx.y * 64 + qs * 32;
  const float qscale = 0.18033688011112042f;  // 0.125 * log2(e)
  const int sw = l31 & 7;

  // Q fragments (B-operand of swapped QK^T): bq[s] = Q[q0w+l31][s*16 + hi*8 + j] * qscale
  const unsigned short* qrow = qkv + (size_t)(b * SEQ + q0w + l31) * QKV3 + h * HDIM;
  bf16x8 bq[4];
#pragma unroll
  for (int s = 0; s < 4; s++) {
    bq[s] = *(const bf16x8*)(qrow + s * 16 + hi * 8);
#pragma unroll
    for (int j = 0; j < 8; j++)
      bq[s][j] = (short)f2bf(bf2f((unsigned short)bq[s][j]) * qscale);
  }
  bf16x8 ones;
#pragma unroll
  for (int j = 0; j < 8; j++) ones[j] = (short)0x3F80;  // bf16 1.0

  f32x16 zz;
#pragma unroll
  for (int i = 0; i < 16; i++) zz[i] = 0.f;
  f32x16 O0 = zz, O1 = zz, lsum = zz;

  // staging: wave stages 16 K-rows (keys) and 16 V-rows (d), pre-swizzled global chunk
  const int skey = lane >> 3;
  const int schunk8 = ((lane & 7) ^ (skey & 7)) * 8;
  const unsigned short* kbase =
      qkv + (size_t)(b * SEQ + wave * 16 + skey) * QKV3 + EMBED + h * HDIM + schunk8;
  const unsigned short* vbase =
      vT + (size_t)(bh * 64 + wave * 16 + skey) * SEQ + schunk8;

  // prologue: stage tile 0 into buffer 0
  gload16(kbase, &Ks[0][wave * 1024]);
  gload16(kbase + (size_t)8 * QKV3, &Ks[0][wave * 1024] + 512);
  gload16(vbase, &Vs[0][wave * 1024]);
  gload16(vbase + (size_t)8 * SEQ, &Vs[0][wave * 1024] + 512);
  __syncthreads();  // vmcnt drain: tile 0 resident

  const int krow0 = kh * 32;  // this wave's 32-key half within the tile
  for (int kti = 0; kti < SEQ / 64; ++kti) {
    const int cur = kti & 1;
    // prefetch next tile (latency hides under this tile's compute)
    if (kti + 1 < SEQ / 64) {
      const int kt = (kti + 1) * 64;
      unsigned short* kd = &Ks[cur ^ 1][wave * 1024];
      unsigned short* vd = &Vs[cur ^ 1][wave * 1024];
      gload16(kbase + (size_t)kt * QKV3, kd);
      gload16(kbase + (size_t)(kt + 8) * QKV3, kd + 512);
      gload16(vbase + kt, vd);
      gload16(vbase + kt + (size_t)8 * SEQ, vd + 512);
    }
    const unsigned short* Kc = &Ks[cur][0];
    const unsigned short* Vc = &Vs[cur][0];

    // QK^T over this wave's 32 keys: St^T[key][q]. A = K rows, B = Q.
    f32x16 St = zz;
#pragma unroll
    for (int s = 0; s < 4; s++) {
      bf16x8 ak = *(const bf16x8*)&Kc[(krow0 + l31) * 64 + ((2 * s + hi) ^ sw) * 8];
      St = __builtin_amdgcn_mfma_f32_32x32x16_bf16(ak, bq[s], St, 0, 0, 0);
    }

    // exp2 + pack: lane holds P[q=l31][key = krow0 + (r&3)+8*(r>>2)+4*hi].
    // W0[g] packs keys (8g+4hi+0, +1); W1[g] packs (+2, +3).
    unsigned W0[4], W1[4];
#pragma unroll
    for (int g = 0; g < 4; g++) {
      W0[g] = pk2bf(fexp2(St[4 * g]), fexp2(St[4 * g + 1]));
      W1[g] = pk2bf(fexp2(St[4 * g + 2]), fexp2(St[4 * g + 3]));
    }

    // T12 assembly: pa[ks] = A-frag P[q=l31][keys krow0 + ks*16 + hi*8 + j]
    bf16x8 pa[2];
#pragma unroll
    for (int ks = 0; ks < 2; ks++) {
      const int g0 = 2 * ks, g1 = g0 + 1;
      unsigned w0, w1, w2, w3;
      halfswap(W0[g0], W0[g1], hi, w0, w2);
      halfswap(W1[g0], W1[g1], hi, w1, w3);
      union { unsigned u[4]; bf16x8 v; } pw;
      pw.u[0] = w0; pw.u[1] = w1; pw.u[2] = w2; pw.u[3] = w3;
      pa[ks] = pw.v;
    }

    // lsum + PV over this wave's keys (rows of D = q, cols = d)
    __builtin_amdgcn_s_setprio(1);
    lsum = __builtin_amdgcn_mfma_f32_32x32x16_bf16(pa[0], ones, lsum, 0, 0, 0);
    lsum = __builtin_amdgcn_mfma_f32_32x32x16_bf16(pa[1], ones, lsum, 0, 0, 0);
#pragma unroll
    for (int ks = 0; ks < 2; ks++) {
      const int ch = kh * 4 + ks * 2 + hi;  // key chunk = key/8
      bf16x8 bv0 = *(const bf16x8*)&Vc[l31 * 64 + (ch ^ sw) * 8];
      bf16x8 bv1 = *(const bf16x8*)&Vc[(32 + l31) * 64 + (ch ^ sw) * 8];
      O0 = __builtin_amdgcn_mfma_f32_32x32x16_bf16(pa[ks], bv0, O0, 0, 0, 0);
      O1 = __builtin_amdgcn_mfma_f32_32x32x16_bf16(pa[ks], bv1, O1, 0, 0, 0);
    }
    __builtin_amdgcn_s_setprio(0);
    __syncthreads();
  }

  // merge key-half partials: waves (qs, kh=1) dump to LDS; waves (qs, kh=0) add + write.
  if (kh == 1) {
    float* sc = qs ? (float*)&Vs[0][0] : (float*)&Ks[0][0];
#pragma unroll
    for (int r = 0; r < 16; r++) {
      sc[lane * 48 + r]      = lsum[r];
      sc[lane * 48 + 16 + r] = O0[r];
      sc[lane * 48 + 32 + r] = O1[r];
    }
  }
  __syncthreads();
  if (kh == 0) {
    const float* sc = qs ? (const float*)&Vs[0][0] : (const float*)&Ks[0][0];
#pragma unroll
    for (int r = 0; r < 16; r++) {
      lsum[r] += sc[lane * 48 + r];
      O0[r]   += sc[lane * 48 + 16 + r];
      O1[r]   += sc[lane * 48 + 32 + r];
    }
#pragma unroll
    for (int r = 0; r < 16; r++) {
      const int qr = (r & 3) + 8 * (r >> 2) + 4 * hi;
      float inv = 1.0f / lsum[r];
      size_t g = (size_t)(b * SEQ + q0w + qr) * EMBED + h * HDIM + l31;
      attn[g]      = f2bf(O0[r] * inv);
      attn[g + 32] = f2bf(O1[r] * inv);
    }
  }
}

extern "C" void kernel_launch(void* const* d_in, const int* in_sizes, int n_in,
                              void* d_out, int out_size, void* d_ws, size_t ws_size,
                              hipStream_t stream) {
  const float* x      = (const float*)d_in[0];
  const float* ln1_w  = (const float*)d_in[1];
  const float* ln1_b  = (const float*)d_in[2];
  const float* ln2_w  = (const float*)d_in[3];
  const float* ln2_b  = (const float*)d_in[4];
  const float* qkv_w  = (const float*)d_in[5];
  const float* qkv_b  = (const float*)d_in[6];
  const float* proj_w = (const float*)d_in[7];
  const float* proj_b = (const float*)d_in[8];
  const float* fc1_w  = (const float*)d_in[9];
  const float* fc1_b  = (const float*)d_in[10];
  const float* fc2_w  = (const float*)d_in[11];
  const float* fc2_b  = (const float*)d_in[12];
  float* out = (float*)d_out;
  char* wsb = (char*)d_ws;
  unsigned short* lnbuf  = (unsigned short*)(wsb + 0);
  unsigned short* qkvb   = (unsigned short*)(wsb + 8388608);
  unsigned short* attnb  = (unsigned short*)(wsb + 33554432);
  unsigned short* vTb    = (unsigned short*)(wsb + 41943040);
  unsigned short* actb   = (unsigned short*)(wsb + 33554432);
  float*          h1     = (float*)(wsb + 67108864);
  unsigned short* qkvWt  = (unsigned short*)(wsb + 83886080);
  unsigned short* projWt = (unsigned short*)(wsb + 90177536);
  unsigned short* fc1Wt  = (unsigned short*)(wsb + 92274688);
  unsigned short* fc2Wt  = (unsigned short*)(wsb + 100663296);

  TD4 td;
  td.d[0] = {qkv_w,  qkvWt,  1024, 3072,  96, 0};
  td.d[1] = {proj_w, projWt, 1024, 1024,  32, 3072};
  td.d[2] = {fc1_w,  fc1Wt,  1024, 4096, 128, 4096};
  td.d[3] = {fc2_w,  fc2Wt,  4096, 1024,  32, 8192};
  transpose_all<<<12288, dim3(32, 8), 0, stream>>>(td);

  ln_kernel<<<MTOK, 256, 0, stream>>>(x, ln1_w, ln1_b, lnbuf);
  gemmBig<0, 1, 1><<<768, 256, 0, stream>>>(
      lnbuf, qkvWt, qkv_b, qkvb, nullptr, vTb, MTOK, QKV3, EMBED, 24);
  attn_kernel<<<dim3(32, 32), 256, 0, stream>>>(qkvb, vTb, attnb);
  gemm64k<1, 0><<<512, 256, 0, stream>>>(
      attnb, projWt, proj_b, x, nullptr, h1, MTOK, EMBED, EMBED, 16);
  ln_kernel<<<MTOK, 256, 0, stream>>>(h1, ln2_w, ln2_b, lnbuf);
  gemmBig<1, 1, 0><<<1024, 256, 0, stream>>>(
      lnbuf, fc1Wt, fc1_b, actb, nullptr, nullptr, MTOK, FFN, EMBED, 32);
  gemm64k<1, 0><<<512, 256, 0, stream>>>(
      actb, fc2Wt, fc2_b, h1, nullptr, out, MTOK, EMBED, FFN, 16);
}

// Round 6
// 339.463 us; speedup vs baseline: 1.0784x; 1.0120x over previous
//
#include <hip/hip_runtime.h>
#include <hip/hip_bf16.h>

#define SEQ    2048
#define BATCH  2
#define MTOK   4096
#define EMBED  1024
#define HEADS  16
#define HDIM   64
#define QKV3   3072
#define FFN    4096

typedef __attribute__((ext_vector_type(8))) short bf16x8;
typedef __attribute__((ext_vector_type(4))) float f32x4;
typedef __attribute__((ext_vector_type(16))) float f32x16;

static __device__ __forceinline__ unsigned short f2bf(float f) {
  union { float f; unsigned u; } x; x.f = f;
  unsigned r = x.u + 0x7FFFu + ((x.u >> 16) & 1u);
  return (unsigned short)(r >> 16);
}
static __device__ __forceinline__ float bf2f(unsigned short u) {
  union { unsigned u; float f; } x; x.u = ((unsigned)u) << 16; return x.f;
}
static __device__ __forceinline__ unsigned pk2bf(float a, float b) {
#if __has_builtin(__builtin_amdgcn_cvt_pk_bf16_f32)
  typedef __attribute__((ext_vector_type(2))) __bf16 bf16x2_t;
  union { bf16x2_t v; unsigned u; } x;
  x.v = __builtin_amdgcn_cvt_pk_bf16_f32(a, b);
  return x.u;
#else
  return ((unsigned)f2bf(a)) | (((unsigned)f2bf(b)) << 16);
#endif
}
static __device__ __forceinline__ float fexp2(float x) {
#if __has_builtin(__builtin_amdgcn_exp2f)
  return __builtin_amdgcn_exp2f(x);
#else
  return exp2f(x);
#endif
}
static __device__ __forceinline__ float frcp(float x) {
#if __has_builtin(__builtin_amdgcn_rcpf)
  return __builtin_amdgcn_rcpf(x);
#else
  return 1.0f / x;
#endif
}
// gelu(v) = v * sigmoid(1.5957691*(v + 0.044715 v^3)); sigmoid via exp2.
static __device__ __forceinline__ float fgelu(float v) {
  float t = v * v;
  float z = v * __builtin_fmaf(-0.1029456f, t, -2.3022650687f);
  return v * frcp(1.0f + fexp2(z));
}

// half-swap across the lane<32 / lane>=32 split:
//   lo_out = concat(a[0:32], b[0:32])   hi_out = concat(a[32:64], b[32:64])
static __device__ __forceinline__ void halfswap(unsigned a, unsigned b, int hi,
                                                unsigned& lo_out, unsigned& hi_out) {
#if __has_builtin(__builtin_amdgcn_permlane32_swap)
  typedef __attribute__((ext_vector_type(2))) unsigned uint2v;
  uint2v r = __builtin_amdgcn_permlane32_swap(a, b, false, false);
  lo_out = r[0];
  hi_out = r[1];
#else
  unsigned as = (unsigned)__shfl_xor((int)a, 32);
  unsigned bs = (unsigned)__shfl_xor((int)b, 32);
  lo_out = hi ? bs : a;
  hi_out = hi ? b : as;
#endif
}

// async global->LDS, 16B per lane; lds dest is wave-uniform base + lane*16
static __device__ __forceinline__ void gload16(const unsigned short* g, unsigned short* l) {
  __builtin_amdgcn_global_load_lds((const __attribute__((address_space(1))) void*)g,
                                   (__attribute__((address_space(3))) void*)l, 16, 0, 0);
}

#define MEMFENCE asm volatile("" ::: "memory")

// ---------------- fused weight transpose + fp32->bf16: Wt[n][k] = W[k][n] (all 4 weights)
struct TD { const float* W; unsigned short* T; int K, N, ntx, base; };
struct TD4 { TD d[4]; };

__global__ void transpose_all(TD4 td) {
  __shared__ float t[32][33];
  int bid = blockIdx.x;
  int i = 0;
  if (bid >= td.d[1].base) i = 1;
  if (bid >= td.d[2].base) i = 2;
  if (bid >= td.d[3].base) i = 3;
  const TD& D = td.d[i];
  int local = bid - D.base;
  int n0 = (local % D.ntx) * 32, k0 = (local / D.ntx) * 32;
  int tx = threadIdx.x, ty = threadIdx.y;  // block (32,8)
#pragma unroll
  for (int j = 0; j < 32; j += 8)
    t[ty + j][tx] = D.W[(size_t)(k0 + ty + j) * D.N + n0 + tx];
  __syncthreads();
#pragma unroll
  for (int j = 0; j < 32; j += 8)
    D.T[(size_t)(n0 + ty + j) * D.K + k0 + tx] = f2bf(t[tx][ty + j]);
}

// ---------------- layernorm (one token per block), fp32 in -> bf16 out
__global__ __launch_bounds__(256) void ln_kernel(const float* __restrict__ in,
                                                 const float* __restrict__ w,
                                                 const float* __restrict__ b,
                                                 unsigned short* __restrict__ out) {
  __shared__ float sh[4];
  int row = blockIdx.x, tid = threadIdx.x;
  const float4 v = ((const float4*)(in + (size_t)row * EMBED))[tid];
  float s = v.x + v.y + v.z + v.w;
#pragma unroll
  for (int off = 32; off; off >>= 1) s += __shfl_xor(s, off);
  if ((tid & 63) == 0) sh[tid >> 6] = s;
  __syncthreads();
  float mean = (sh[0] + sh[1] + sh[2] + sh[3]) * (1.0f / EMBED);
  __syncthreads();
  float dx = v.x - mean, dy = v.y - mean, dz = v.z - mean, dw = v.w - mean;
  float q = dx * dx + dy * dy + dz * dz + dw * dw;
#pragma unroll
  for (int off = 32; off; off >>= 1) q += __shfl_xor(q, off);
  if ((tid & 63) == 0) sh[tid >> 6] = q;
  __syncthreads();
  float var = (sh[0] + sh[1] + sh[2] + sh[3]) * (1.0f / EMBED);
  float rs = rsqrtf(var + 1e-5f);
  const float4 wv = ((const float4*)w)[tid];
  const float4 bv = ((const float4*)b)[tid];
  ushort4 o;
  o.x = f2bf(dx * rs * wv.x + bv.x);
  o.y = f2bf(dy * rs * wv.y + bv.y);
  o.z = f2bf(dz * rs * wv.z + bv.z);
  o.w = f2bf(dw * rs * wv.w + bv.w);
  ((ushort4*)(out + (size_t)row * EMBED))[tid] = o;
}

// ---------------- 128x128 NT bf16 GEMM, BK=64, XOR-swizzled LDS (128B rows),
// plain n-fastest block order (XCD x statically owns n === x mod 8 -> B slice L2-resident).
template <int ACT, int OUTBF, int VSPLIT>
__global__ __launch_bounds__(256) void gemmBig(const unsigned short* __restrict__ A,
                                               const unsigned short* __restrict__ Wt,
                                               const float* __restrict__ bias,
                                               unsigned short* __restrict__ outB,
                                               float* __restrict__ outF,
                                               unsigned short* __restrict__ vT,
                                               int M, int N, int K, int nblk) {
  __shared__ __align__(16) unsigned short As[128 * 64];  // 16 KB
  __shared__ __align__(16) unsigned short Bs[128 * 64];  // 16 KB
  const int tid = threadIdx.x;
  const int wave = tid >> 6, lane = tid & 63;
  const int quad = lane >> 4, ml = lane & 15;
  const int wr = wave >> 1, wc = wave & 1;
  const int m0 = (blockIdx.x / nblk) * 128;
  const int n0 = (blockIdx.x % nblk) * 128;
  const int srow = lane >> 3;
  const int schunk = (lane & 7) ^ (srow & 7);
  const unsigned short* Ag = A + (size_t)(m0 + wave * 32 + srow) * K + schunk * 8;
  const unsigned short* Bg = Wt + (size_t)(n0 + wave * 32 + srow) * K + schunk * 8;
  unsigned short* AsW = &As[wave * 2048];
  unsigned short* BsW = &Bs[wave * 2048];
  f32x4 acc[4][4];
#pragma unroll
  for (int i = 0; i < 4; i++)
#pragma unroll
    for (int j = 0; j < 4; j++) acc[i][j] = (f32x4){0.f, 0.f, 0.f, 0.f};
  for (int k0 = 0; k0 < K; k0 += 64) {
    __syncthreads();
#pragma unroll
    for (int t = 0; t < 4; t++) {
      gload16(Ag + (size_t)(8 * t) * K, AsW + 512 * t);
      gload16(Bg + (size_t)(8 * t) * K, BsW + 512 * t);
    }
    Ag += 64; Bg += 64;
    __syncthreads();
#pragma unroll
    for (int kh = 0; kh < 2; kh++) {
      const int ch = ((kh * 4 + quad) ^ (ml & 7)) * 8;
      bf16x8 af[4], bfr[4];
#pragma unroll
      for (int mt = 0; mt < 4; mt++)
        af[mt] = *(const bf16x8*)&As[(wr * 64 + mt * 16 + ml) * 64 + ch];
#pragma unroll
      for (int nt = 0; nt < 4; nt++)
        bfr[nt] = *(const bf16x8*)&Bs[(wc * 64 + nt * 16 + ml) * 64 + ch];
#pragma unroll
      for (int mt = 0; mt < 4; mt++)
#pragma unroll
        for (int nt = 0; nt < 4; nt++)
          acc[mt][nt] = __builtin_amdgcn_mfma_f32_16x16x32_bf16(af[mt], bfr[nt], acc[mt][nt], 0, 0, 0);
    }
  }
#pragma unroll
  for (int mt = 0; mt < 4; mt++)
#pragma unroll
    for (int nt = 0; nt < 4; nt++) {
      const int col0 = n0 + wc * 64 + nt * 16;
      const int row0 = m0 + wr * 64 + mt * 16;
      if (VSPLIT && col0 >= 2 * EMBED) {
        const int b = row0 >> 11, tok0 = row0 & (SEQ - 1);
        const int h = (col0 - 2 * EMBED) >> 6;
        const int dl = ((col0 - 2 * EMBED) & 63) + ml;
        float bia = bias[col0 + ml];
        ushort4 o;
        o.x = f2bf(acc[mt][nt][0] + bia);
        o.y = f2bf(acc[mt][nt][1] + bia);
        o.z = f2bf(acc[mt][nt][2] + bia);
        o.w = f2bf(acc[mt][nt][3] + bia);
        *(ushort4*)(vT + (size_t)((b * 16 + h) * 64 + dl) * SEQ + tok0 + quad * 4) = o;
      } else {
#pragma unroll
        for (int r = 0; r < 4; r++) {
          int row = row0 + quad * 4 + r;
          int col = col0 + ml;
          float v = acc[mt][nt][r] + bias[col];
          if (ACT) v = fgelu(v);
          if (OUTBF)
            outB[(size_t)row * N + col] = f2bf(v);
          else
            outF[(size_t)row * N + col] = v;
        }
      }
    }
}

// ---------------- 256x256 8-phase GEMM (T3+T4+T2+T5), BK=64, dual K-tile slots.
// 8 waves (2M x 4N), 512 threads, LDS 128 KB -> 1 block/CU (2 waves/SIMD).
// Per iteration: 2 K-tiles (K += 128), 8 phases; phase = {pre-issued ds_reads ||
// 2 gload16 staging -> [publish: vmcnt(2)] -> barrier -> 16 MFMA (setprio) -> barrier}.
// Staging ledger: slot s holds K-tile t (t&1 == s). K-tile 2i+1 staged ph0-3 (2 loads/ph),
// published at ph4's vmcnt(2); K-tile 2i+2 staged ph4-7, published at next iter ph0's
// vmcnt(2). vmcnt(2) = own 2 just-issued loads remain; the published slot's 8 are older.
// Last-iter publishes use vmcnt(0) (nothing newer in flight). Row-chunk XOR swizzle
// (proven: bank conflicts = 0 in gemmBig) on both stage-source and read side.
__global__ __launch_bounds__(512, 2) void gemm256(const unsigned short* __restrict__ A,
                                                  const unsigned short* __restrict__ Wt,
                                                  const float* __restrict__ bias,
                                                  unsigned short* __restrict__ outB,
                                                  int M, int N, int K, int nblk) {
  __shared__ __align__(16) unsigned short As[2][256 * 64];  // 64 KB
  __shared__ __align__(16) unsigned short Bs[2][256 * 64];  // 64 KB
  const int tid = threadIdx.x;
  const int wave = tid >> 6, lane = tid & 63;
  const int quad = lane >> 4, ml = lane & 15;
  const int wr = wave >> 2, wc = wave & 3;  // 2M x 4N wave grid
  const int m0 = (blockIdx.x / nblk) * 256;
  const int n0 = (blockIdx.x % nblk) * 256;
  const int srow = lane >> 3;
  const int schunk = (lane & 7) ^ (srow & 7);
  // staging: wave stages its own 32-row band of A and of B per K-tile (4+4 gload16)
  const unsigned short* Ag = A  + (size_t)(m0 + wave * 32 + srow) * K + schunk * 8;
  const unsigned short* Bg = Wt + (size_t)(n0 + wave * 32 + srow) * K + schunk * 8;
  f32x4 acc[8][4];
#pragma unroll
  for (int i = 0; i < 8; i++)
#pragma unroll
    for (int j = 0; j < 4; j++) acc[i][j] = (f32x4){0.f, 0.f, 0.f, 0.f};

  // prologue: stage K-tile 0 -> slot 0 (8 gload16/wave)
#pragma unroll
  for (int g = 0; g < 4; g++) {
    gload16(Ag + (size_t)(g * 8) * K, &As[0][(wave * 32 + g * 8) * 64]);
    gload16(Bg + (size_t)(g * 8) * K, &Bs[0][(wave * 32 + g * 8) * 64]);
  }

  const int nit = K >> 7;  // 2 K-tiles per iteration
  for (int it = 0; it < nit; ++it) {
#pragma unroll
    for (int half = 0; half < 2; ++half) {
      const int rs = half;                 // slot being read this half
      const int ss = half ^ 1;             // slot being staged this half
      const int kst = 2 * it + 1 + half;   // K-tile being staged
      const bool doStage = (kst < 2 * nit);
      const unsigned short* Asl = &As[rs][0];
      const unsigned short* Bsl = &Bs[rs][0];
      bf16x8 bfr[4][2];
#pragma unroll
      for (int ph = 0; ph < 4; ++ph) {
        bf16x8 af[2][2];
        // pre-issue this phase's A-frag reads (data published at this half's ph0 barrier)
        if (ph > 0) {
#pragma unroll
          for (int mt2 = 0; mt2 < 2; ++mt2)
#pragma unroll
            for (int kk = 0; kk < 2; ++kk)
              af[mt2][kk] = *(const bf16x8*)&Asl[(wr * 128 + (ph * 2 + mt2) * 16 + ml) * 64 +
                                                ((kk * 4 + quad) ^ (ml & 7)) * 8];
        }
        // stage pair into slot ss (phases 0-1: A band halves; 2-3: B band halves)
        if (doStage) {
          if (ph < 2) {
            gload16(Ag + (size_t)((ph * 2) * 8) * K + kst * 64,
                    &As[ss][(wave * 32 + (ph * 2) * 8) * 64]);
            gload16(Ag + (size_t)((ph * 2 + 1) * 8) * K + kst * 64,
                    &As[ss][(wave * 32 + (ph * 2 + 1) * 8) * 64]);
          } else {
            gload16(Bg + (size_t)(((ph - 2) * 2) * 8) * K + kst * 64,
                    &Bs[ss][(wave * 32 + ((ph - 2) * 2) * 8) * 64]);
            gload16(Bg + (size_t)(((ph - 2) * 2 + 1) * 8) * K + kst * 64,
                    &Bs[ss][(wave * 32 + ((ph - 2) * 2 + 1) * 8) * 64]);
          }
        }
        if (ph == 0) {
          // publish slot rs: wait its 8 staging loads (own 2 newest may stay in flight)
          if (doStage) { asm volatile("s_waitcnt vmcnt(2)" ::: "memory"); }
          else         { asm volatile("s_waitcnt vmcnt(0)" ::: "memory"); }
          MEMFENCE; __builtin_amdgcn_s_barrier(); MEMFENCE;
          // now safe to read: B-frags for the whole half (8) + A quad0 (4)
#pragma unroll
          for (int nt = 0; nt < 4; ++nt)
#pragma unroll
            for (int kk = 0; kk < 2; ++kk)
              bfr[nt][kk] = *(const bf16x8*)&Bsl[(wc * 64 + nt * 16 + ml) * 64 +
                                                ((kk * 4 + quad) ^ (ml & 7)) * 8];
#pragma unroll
          for (int mt2 = 0; mt2 < 2; ++mt2)
#pragma unroll
            for (int kk = 0; kk < 2; ++kk)
              af[mt2][kk] = *(const bf16x8*)&Asl[(wr * 128 + mt2 * 16 + ml) * 64 +
                                                ((kk * 4 + quad) ^ (ml & 7)) * 8];
        } else {
          MEMFENCE; __builtin_amdgcn_s_barrier(); MEMFENCE;
        }
        __builtin_amdgcn_s_setprio(1);
#pragma unroll
        for (int mt2 = 0; mt2 < 2; ++mt2)
#pragma unroll
          for (int nt = 0; nt < 4; ++nt)
#pragma unroll
            for (int kk = 0; kk < 2; ++kk)
              acc[ph * 2 + mt2][nt] = __builtin_amdgcn_mfma_f32_16x16x32_bf16(
                  af[mt2][kk], bfr[nt][kk], acc[ph * 2 + mt2][nt], 0, 0, 0);
        __builtin_amdgcn_s_setprio(0);
        MEMFENCE; __builtin_amdgcn_s_barrier(); MEMFENCE;
      }
    }
  }
  // epilogue: bias + gelu + bf16 store
#pragma unroll
  for (int mt = 0; mt < 8; ++mt)
#pragma unroll
    for (int nt = 0; nt < 4; ++nt)
#pragma unroll
      for (int r = 0; r < 4; ++r) {
        int row = m0 + wr * 128 + mt * 16 + quad * 4 + r;
        int col = n0 + wc * 64 + nt * 16 + ml;
        float v = acc[mt][nt][r] + bias[col];
        v = fgelu(v);
        outB[(size_t)row * N + col] = f2bf(v);
      }
}

// ---------------- 128x64 NT GEMM, BK=64, XOR-swizzled LDS, XCD m-stripe grid.
// v3: 2-phase double-buffered prefetch (T3-min): grid shape-pinned at 2 blocks/CU,
// prefetch-before-compute + one barrier/iter reclaims exposed stage latency.
template <int RES, int OUTBF>
__global__ __launch_bounds__(256) void gemm64k(const unsigned short* __restrict__ A,
                                               const unsigned short* __restrict__ Wt,
                                               const float* __restrict__ bias,
                                               const float* __restrict__ res,
                                               unsigned short* __restrict__ outB,
                                               float* __restrict__ outF,
                                               int M, int N, int K, int nblk) {
  __shared__ __align__(16) unsigned short As[2][128 * 64];  // 32 KB
  __shared__ __align__(16) unsigned short Bs[2][64 * 64];   // 16 KB
  const int tid = threadIdx.x;
  const int wave = tid >> 6, lane = tid & 63;
  const int quad = lane >> 4, ml = lane & 15;
  const int wr = wave >> 1, wc = wave & 1;
  const int xcd = blockIdx.x & 7, idx = blockIdx.x >> 3;
  const int mPerXcd = (gridDim.x >> 3) / nblk;
  const int m0 = (xcd * mPerXcd + idx / nblk) * 128;
  const int n0 = (idx % nblk) * 64;
  const int srow = lane >> 3;
  const int schunk = (lane & 7) ^ (srow & 7);
  const unsigned short* Ag = A + (size_t)(m0 + wave * 32 + srow) * K + schunk * 8;
  const unsigned short* Bg = Wt + (size_t)(n0 + wave * 16 + srow) * K + schunk * 8;
  f32x4 acc[4][2];
#pragma unroll
  for (int i = 0; i < 4; i++) { acc[i][0] = (f32x4){0.f,0.f,0.f,0.f}; acc[i][1] = acc[i][0]; }
  {
    unsigned short* AsW = &As[0][wave * 2048];
    unsigned short* BsW = &Bs[0][wave * 1024];
    gload16(Ag, AsW);
    gload16(Ag + (size_t)8 * K,  AsW + 512);
    gload16(Ag + (size_t)16 * K, AsW + 1024);
    gload16(Ag + (size_t)24 * K, AsW + 1536);
    gload16(Bg, BsW);
    gload16(Bg + (size_t)8 * K,  BsW + 512);
    Ag += 64; Bg += 64;
  }
  __syncthreads();
  const int nk = K >> 6;
  for (int kk = 0; kk < nk; ++kk) {
    const int cur = kk & 1;
    if (kk + 1 < nk) {
      unsigned short* AsW = &As[cur ^ 1][wave * 2048];
      unsigned short* BsW = &Bs[cur ^ 1][wave * 1024];
      gload16(Ag, AsW);
      gload16(Ag + (size_t)8 * K,  AsW + 512);
      gload16(Ag + (size_t)16 * K, AsW + 1024);
      gload16(Ag + (size_t)24 * K, AsW + 1536);
      gload16(Bg, BsW);
      gload16(Bg + (size_t)8 * K,  BsW + 512);
      Ag += 64; Bg += 64;
    }
#pragma unroll
    for (int kh = 0; kh < 2; kh++) {
      const int ch = ((kh * 4 + quad) ^ (ml & 7)) * 8;
      bf16x8 af[4], bfr[2];
#pragma unroll
      for (int mt = 0; mt < 4; mt++)
        af[mt] = *(const bf16x8*)&As[cur][(wr * 64 + mt * 16 + ml) * 64 + ch];
#pragma unroll
      for (int nt = 0; nt < 2; nt++)
        bfr[nt] = *(const bf16x8*)&Bs[cur][(wc * 32 + nt * 16 + ml) * 64 + ch];
#pragma unroll
      for (int mt = 0; mt < 4; mt++)
#pragma unroll
        for (int nt = 0; nt < 2; nt++)
          acc[mt][nt] = __builtin_amdgcn_mfma_f32_16x16x32_bf16(af[mt], bfr[nt], acc[mt][nt], 0, 0, 0);
    }
    __syncthreads();
  }
#pragma unroll
  for (int mt = 0; mt < 4; mt++)
#pragma unroll
    for (int nt = 0; nt < 2; nt++)
#pragma unroll
      for (int r = 0; r < 4; r++) {
        int row = m0 + wr * 64 + mt * 16 + quad * 4 + r;
        int col = n0 + wc * 32 + nt * 16 + ml;
        float v = acc[mt][nt][r] + bias[col];
        if (RES) v += res[(size_t)row * N + col];
        if (OUTBF)
          outB[(size_t)row * N + col] = f2bf(v);
        else
          outF[(size_t)row * N + col] = v;
      }
}

// ---------------- flash attention v4: 32x32x16 MFMA + in-reg softmax + KEY-SPLIT waves.
// (unchanged from round 5 — 63.4 us, near its current-structure ceiling)
__global__ __launch_bounds__(256, 4) void attn_kernel(const unsigned short* __restrict__ qkv,
                                                      const unsigned short* __restrict__ vT,
                                                      unsigned short* __restrict__ attn) {
  __shared__ __align__(16) unsigned short Ks[2][64 * 64];  // 16 KB
  __shared__ __align__(16) unsigned short Vs[2][64 * 64];  // 16 KB
  const int tid = threadIdx.x, wave = tid >> 6, lane = tid & 63;
  const int l31 = lane & 31, hi = lane >> 5;
  const int qs = wave & 1, kh = wave >> 1;
  const int bh = blockIdx.x, b = bh >> 4, h = bh & 15;   // bh = fast grid axis
  const int q0w = blockIdx.y * 64 + qs * 32;
  const float qscale = 0.18033688011112042f;  // 0.125 * log2(e)
  const int sw = l31 & 7;

  const unsigned short* qrow = qkv + (size_t)(b * SEQ + q0w + l31) * QKV3 + h * HDIM;
  bf16x8 bq[4];
#pragma unroll
  for (int s = 0; s < 4; s++) {
    bq[s] = *(const bf16x8*)(qrow + s * 16 + hi * 8);
#pragma unroll
    for (int j = 0; j < 8; j++)
      bq[s][j] = (short)f2bf(bf2f((unsigned short)bq[s][j]) * qscale);
  }
  bf16x8 ones;
#pragma unroll
  for (int j = 0; j < 8; j++) ones[j] = (short)0x3F80;  // bf16 1.0

  f32x16 zz;
#pragma unroll
  for (int i = 0; i < 16; i++) zz[i] = 0.f;
  f32x16 O0 = zz, O1 = zz, lsum = zz;

  const int skey = lane >> 3;
  const int schunk8 = ((lane & 7) ^ (skey & 7)) * 8;
  const unsigned short* kbase =
      qkv + (size_t)(b * SEQ + wave * 16 + skey) * QKV3 + EMBED + h * HDIM + schunk8;
  const unsigned short* vbase =
      vT + (size_t)(bh * 64 + wave * 16 + skey) * SEQ + schunk8;

  gload16(kbase, &Ks[0][wave * 1024]);
  gload16(kbase + (size_t)8 * QKV3, &Ks[0][wave * 1024] + 512);
  gload16(vbase, &Vs[0][wave * 1024]);
  gload16(vbase + (size_t)8 * SEQ, &Vs[0][wave * 1024] + 512);
  __syncthreads();

  const int krow0 = kh * 32;
  for (int kti = 0; kti < SEQ / 64; ++kti) {
    const int cur = kti & 1;
    if (kti + 1 < SEQ / 64) {
      const int kt = (kti + 1) * 64;
      unsigned short* kd = &Ks[cur ^ 1][wave * 1024];
      unsigned short* vd = &Vs[cur ^ 1][wave * 1024];
      gload16(kbase + (size_t)kt * QKV3, kd);
      gload16(kbase + (size_t)(kt + 8) * QKV3, kd + 512);
      gload16(vbase + kt, vd);
      gload16(vbase + kt + (size_t)8 * SEQ, vd + 512);
    }
    const unsigned short* Kc = &Ks[cur][0];
    const unsigned short* Vc = &Vs[cur][0];

    f32x16 St = zz;
#pragma unroll
    for (int s = 0; s < 4; s++) {
      bf16x8 ak = *(const bf16x8*)&Kc[(krow0 + l31) * 64 + ((2 * s + hi) ^ sw) * 8];
      St = __builtin_amdgcn_mfma_f32_32x32x16_bf16(ak, bq[s], St, 0, 0, 0);
    }

    unsigned W0[4], W1[4];
#pragma unroll
    for (int g = 0; g < 4; g++) {
      W0[g] = pk2bf(fexp2(St[4 * g]), fexp2(St[4 * g + 1]));
      W1[g] = pk2bf(fexp2(St[4 * g + 2]), fexp2(St[4 * g + 3]));
    }

    bf16x8 pa[2];
#pragma unroll
    for (int ks = 0; ks < 2; ks++) {
      const int g0 = 2 * ks, g1 = g0 + 1;
      unsigned w0, w1, w2, w3;
      halfswap(W0[g0], W0[g1], hi, w0, w2);
      halfswap(W1[g0], W1[g1], hi, w1, w3);
      union { unsigned u[4]; bf16x8 v; } pw;
      pw.u[0] = w0; pw.u[1] = w1; pw.u[2] = w2; pw.u[3] = w3;
      pa[ks] = pw.v;
    }

    __builtin_amdgcn_s_setprio(1);
    lsum = __builtin_amdgcn_mfma_f32_32x32x16_bf16(pa[0], ones, lsum, 0, 0, 0);
    lsum = __builtin_amdgcn_mfma_f32_32x32x16_bf16(pa[1], ones, lsum, 0, 0, 0);
#pragma unroll
    for (int ks = 0; ks < 2; ks++) {
      const int ch = kh * 4 + ks * 2 + hi;
      bf16x8 bv0 = *(const bf16x8*)&Vc[l31 * 64 + (ch ^ sw) * 8];
      bf16x8 bv1 = *(const bf16x8*)&Vc[(32 + l31) * 64 + (ch ^ sw) * 8];
      O0 = __builtin_amdgcn_mfma_f32_32x32x16_bf16(pa[ks], bv0, O0, 0, 0, 0);
      O1 = __builtin_amdgcn_mfma_f32_32x32x16_bf16(pa[ks], bv1, O1, 0, 0, 0);
    }
    __builtin_amdgcn_s_setprio(0);
    __syncthreads();
  }

  if (kh == 1) {
    float* sc = qs ? (float*)&Vs[0][0] : (float*)&Ks[0][0];
#pragma unroll
    for (int r = 0; r < 16; r++) {
      sc[lane * 48 + r]      = lsum[r];
      sc[lane * 48 + 16 + r] = O0[r];
      sc[lane * 48 + 32 + r] = O1[r];
    }
  }
  __syncthreads();
  if (kh == 0) {
    const float* sc = qs ? (const float*)&Vs[0][0] : (const float*)&Ks[0][0];
#pragma unroll
    for (int r = 0; r < 16; r++) {
      lsum[r] += sc[lane * 48 + r];
      O0[r]   += sc[lane * 48 + 16 + r];
      O1[r]   += sc[lane * 48 + 32 + r];
    }
#pragma unroll
    for (int r = 0; r < 16; r++) {
      const int qr = (r & 3) + 8 * (r >> 2) + 4 * hi;
      float inv = 1.0f / lsum[r];
      size_t g = (size_t)(b * SEQ + q0w + qr) * EMBED + h * HDIM + l31;
      attn[g]      = f2bf(O0[r] * inv);
      attn[g + 32] = f2bf(O1[r] * inv);
    }
  }
}

extern "C" void kernel_launch(void* const* d_in, const int* in_sizes, int n_in,
                              void* d_out, int out_size, void* d_ws, size_t ws_size,
                              hipStream_t stream) {
  const float* x      = (const float*)d_in[0];
  const float* ln1_w  = (const float*)d_in[1];
  const float* ln1_b  = (const float*)d_in[2];
  const float* ln2_w  = (const float*)d_in[3];
  const float* ln2_b  = (const float*)d_in[4];
  const float* qkv_w  = (const float*)d_in[5];
  const float* qkv_b  = (const float*)d_in[6];
  const float* proj_w = (const float*)d_in[7];
  const float* proj_b = (const float*)d_in[8];
  const float* fc1_w  = (const float*)d_in[9];
  const float* fc1_b  = (const float*)d_in[10];
  const float* fc2_w  = (const float*)d_in[11];
  const float* fc2_b  = (const float*)d_in[12];
  float* out = (float*)d_out;
  char* wsb = (char*)d_ws;
  unsigned short* lnbuf  = (unsigned short*)(wsb + 0);
  unsigned short* qkvb   = (unsigned short*)(wsb + 8388608);
  unsigned short* attnb  = (unsigned short*)(wsb + 33554432);
  unsigned short* vTb    = (unsigned short*)(wsb + 41943040);
  unsigned short* actb   = (unsigned short*)(wsb + 33554432);
  float*          h1     = (float*)(wsb + 67108864);
  unsigned short* qkvWt  = (unsigned short*)(wsb + 83886080);
  unsigned short* projWt = (unsigned short*)(wsb + 90177536);
  unsigned short* fc1Wt  = (unsigned short*)(wsb + 92274688);
  unsigned short* fc2Wt  = (unsigned short*)(wsb + 100663296);

  TD4 td;
  td.d[0] = {qkv_w,  qkvWt,  1024, 3072,  96, 0};
  td.d[1] = {proj_w, projWt, 1024, 1024,  32, 3072};
  td.d[2] = {fc1_w,  fc1Wt,  1024, 4096, 128, 4096};
  td.d[3] = {fc2_w,  fc2Wt,  4096, 1024,  32, 8192};
  transpose_all<<<12288, dim3(32, 8), 0, stream>>>(td);

  ln_kernel<<<MTOK, 256, 0, stream>>>(x, ln1_w, ln1_b, lnbuf);
  gemmBig<0, 1, 1><<<768, 256, 0, stream>>>(
      lnbuf, qkvWt, qkv_b, qkvb, nullptr, vTb, MTOK, QKV3, EMBED, 24);
  attn_kernel<<<dim3(32, 32), 256, 0, stream>>>(qkvb, vTb, attnb);
  gemm64k<1, 0><<<512, 256, 0, stream>>>(
      attnb, projWt, proj_b, x, nullptr, h1, MTOK, EMBED, EMBED, 16);
  ln_kernel<<<MTOK, 256, 0, stream>>>(h1, ln2_w, ln2_b, lnbuf);
  gemm256<<<256, 512, 0, stream>>>(
      lnbuf, fc1Wt, fc1_b, actb, MTOK, FFN, EMBED, 16);
  gemm64k<1, 0><<<512, 256, 0, stream>>>(
      actb, fc2Wt, fc2_b, h1, nullptr, out, MTOK, EMBED, FFN, 16);
}